// Round 1
// baseline (1007.585 us; speedup 1.0000x reference)
//
#include <hip/hip_runtime.h>
#include <math.h>

#define B_ 4096
#define D_ 512
#define G_ 128
#define N_ (G_*G_)        // 16384
#define NT 128            // number of 128-wide n tiles
#define THR_ 0.95f
#define IMAX_ 0x7FFFFFFF

// ---------------- wnorm: ||w_n||^2 for each SOM cell ----------------
__global__ __launch_bounds__(64) void wnorm_kernel(const float* __restrict__ W,
                                                   float* __restrict__ wnorm) {
    int n = blockIdx.x;
    int t = threadIdx.x;  // 64 threads, one wave
    const float4* row = (const float4*)(W + (size_t)n * D_);
    float4 a = row[t];
    float4 b = row[t + 64];
    float s = a.x*a.x + a.y*a.y + a.z*a.z + a.w*a.w
            + b.x*b.x + b.y*b.y + b.z*b.z + b.w*b.w;
    #pragma unroll
    for (int off = 32; off > 0; off >>= 1) s += __shfl_down(s, off, 64);
    if (t == 0) wnorm[n] = s;
}

// ---------------- fused GEMM + per-tile argmin ----------------
// score[b][n] = wnorm[n] - 2 * dot(A[b], W[n])   (x_norm added later; constant per row)
#define BM 128
#define BN 128
#define BK 32
#define LDA 132   // padded LDS stride (multiple of 4 floats -> 16B-aligned b128 reads)

__global__ __launch_bounds__(256) void score_kernel(
    const float* __restrict__ A, const float* __restrict__ W,
    const float* __restrict__ wnorm,
    const int* __restrict__ labels, const int* __restrict__ clabels,
    float* __restrict__ pminv, int* __restrict__ pmini,
    float* __restrict__ pcminv, int* __restrict__ pcmini)
{
    __shared__ __align__(16) float smem[2 * BK * LDA];  // 33792 B
    float* As = smem;
    float* Bs = smem + BK * LDA;

    const int tid = threadIdx.x;
    const int tx = tid & 15, ty = tid >> 4;
    const int m0 = blockIdx.y * BM;
    const int n0 = blockIdx.x * BN;

    float acc[8][8];
    #pragma unroll
    for (int i = 0; i < 8; i++)
        #pragma unroll
        for (int j = 0; j < 8; j++) acc[i][j] = 0.f;

    for (int k0 = 0; k0 < D_; k0 += BK) {
        float4 av[4], bv[4];
        #pragma unroll
        for (int i = 0; i < 4; i++) {
            int q = tid + i * 256;        // 0..1023
            int row = q >> 3;             // 0..127
            int kq = (q & 7) << 2;        // 0,4,...,28
            av[i] = *(const float4*)(A + (size_t)(m0 + row) * D_ + k0 + kq);
            bv[i] = *(const float4*)(W + (size_t)(n0 + row) * D_ + k0 + kq);
        }
        __syncthreads();   // previous compute done reading LDS
        #pragma unroll
        for (int i = 0; i < 4; i++) {
            int q = tid + i * 256;
            int row = q >> 3;
            int kq = (q & 7) << 2;
            As[(kq+0)*LDA + row] = av[i].x; As[(kq+1)*LDA + row] = av[i].y;
            As[(kq+2)*LDA + row] = av[i].z; As[(kq+3)*LDA + row] = av[i].w;
            Bs[(kq+0)*LDA + row] = bv[i].x; Bs[(kq+1)*LDA + row] = bv[i].y;
            Bs[(kq+2)*LDA + row] = bv[i].z; Bs[(kq+3)*LDA + row] = bv[i].w;
        }
        __syncthreads();
        #pragma unroll 8
        for (int k = 0; k < BK; k++) {
            float4 a0 = *(const float4*)&As[k*LDA + ty*4];
            float4 a1 = *(const float4*)&As[k*LDA + 64 + ty*4];
            float4 b0 = *(const float4*)&Bs[k*LDA + tx*4];
            float4 b1 = *(const float4*)&Bs[k*LDA + 64 + tx*4];
            float am[8] = {a0.x,a0.y,a0.z,a0.w,a1.x,a1.y,a1.z,a1.w};
            float bn[8] = {b0.x,b0.y,b0.z,b0.w,b1.x,b1.y,b1.z,b1.w};
            #pragma unroll
            for (int i = 0; i < 8; i++)
                #pragma unroll
                for (int j = 0; j < 8; j++)
                    acc[i][j] += am[i] * bn[j];
        }
    }
    __syncthreads();   // before reusing smem for reduction

    int mloc[8], nloc[8];
    #pragma unroll
    for (int i = 0; i < 4; i++) {
        mloc[i] = ty*4 + i;  mloc[i+4] = 64 + ty*4 + i;
        nloc[i] = tx*4 + i;  nloc[i+4] = 64 + tx*4 + i;
    }
    float wn[8]; int cl[8], lb[8];
    #pragma unroll
    for (int j = 0; j < 8; j++) { wn[j] = wnorm[n0 + nloc[j]]; cl[j] = clabels[n0 + nloc[j]]; }
    #pragma unroll
    for (int i = 0; i < 8; i++) lb[i] = labels[m0 + mloc[i]];

    float* redv  = smem;                       // [16][128]
    int*   redi  = (int*)(smem + 2048);
    float* credv = smem + 4096;
    int*   credi = (int*)(smem + 6144);

    #pragma unroll
    for (int i = 0; i < 8; i++) {
        float bvv = INFINITY; int bii = IMAX_;
        float cbv = INFINITY; int cbi = IMAX_;
        #pragma unroll
        for (int j = 0; j < 8; j++) {
            int ng = n0 + nloc[j];
            float s = wn[j] - 2.0f * acc[i][j];
            if (s < bvv || (s == bvv && ng < bii)) { bvv = s; bii = ng; }
            float cs = (cl[j] == lb[i]) ? s : INFINITY;
            if (cs < cbv || (cs == cbv && ng < cbi)) { cbv = cs; cbi = ng; }
        }
        redv[tx*128 + mloc[i]] = bvv;  redi[tx*128 + mloc[i]] = bii;
        credv[tx*128 + mloc[i]] = cbv; credi[tx*128 + mloc[i]] = cbi;
    }
    __syncthreads();
    if (tid < 128) {
        int m = tid;
        float bvv = INFINITY; int bii = IMAX_;
        float cbv = INFINITY; int cbi = IMAX_;
        #pragma unroll
        for (int j = 0; j < 16; j++) {
            float v = redv[j*128 + m]; int idx = redi[j*128 + m];
            if (v < bvv || (v == bvv && idx < bii)) { bvv = v; bii = idx; }
            v = credv[j*128 + m]; idx = credi[j*128 + m];
            if (v < cbv || (v == cbv && idx < cbi)) { cbv = v; cbi = idx; }
        }
        size_t p = (size_t)(m0 + m) * NT + blockIdx.x;
        pminv[p] = bvv; pmini[p] = bii; pcminv[p] = cbv; pcmini[p] = cbi;
    }
}

// ---------------- reduce partials per row; emit bmu, sum(min_dists), som_errors ----------------
__global__ __launch_bounds__(128) void reduce_kernel(
    const float* __restrict__ A, const float* __restrict__ W,
    const float* __restrict__ crel,
    const float* __restrict__ pminv, const int* __restrict__ pmini,
    const float* __restrict__ pcminv, const int* __restrict__ pcmini,
    int* __restrict__ bmu, float* __restrict__ sum_min, float* __restrict__ out0)
{
    int b = blockIdx.x, t = threadIdx.x;  // 128 threads, one tile each
    __shared__ float sv[128]; __shared__ int si[128];
    __shared__ float scv[128]; __shared__ int sci[128];
    __shared__ float xs[128];
    __shared__ int   cbmu_s;

    size_t p = (size_t)b * NT + t;
    sv[t] = pminv[p]; si[t] = pmini[p]; scv[t] = pcminv[p]; sci[t] = pcmini[p];

    float4 x4 = ((const float4*)(A + (size_t)b * D_))[t];
    xs[t] = x4.x*x4.x + x4.y*x4.y + x4.z*x4.z + x4.w*x4.w;
    __syncthreads();
    for (int s = 64; s > 0; s >>= 1) {
        if (t < s) {
            float v = sv[t+s]; int idx = si[t+s];
            if (v < sv[t] || (v == sv[t] && idx < si[t])) { sv[t] = v; si[t] = idx; }
            v = scv[t+s]; idx = sci[t+s];
            if (v < scv[t] || (v == scv[t] && idx < sci[t])) { scv[t] = v; sci[t] = idx; }
            xs[t] += xs[t+s];
        }
        __syncthreads();
    }
    if (t == 0) {
        bmu[b] = si[0];
        float md = xs[0] + sv[0];
        if (md < 0.f) md = 0.f;
        atomicAdd(sum_min, md);
        cbmu_s = sci[0];
    }
    __syncthreads();
    int cb = cbmu_s;
    float r = crel[cb] / 100.0f;
    float val = (r >= THR_) ? 1.0f : 0.0f;
    float sc = 0.01f * r * val;
    float4 w4 = ((const float4*)(W + (size_t)cb * D_))[t];
    float4 o;
    o.x = sc * (w4.x - x4.x); o.y = sc * (w4.y - x4.y);
    o.z = sc * (w4.z - x4.z); o.w = sc * (w4.w - x4.w);
    ((float4*)(out0 + (size_t)b * D_))[t] = o;
}

// ---------------- neighborhood scatter (atomic) ----------------
__global__ __launch_bounds__(512) void scatter_kernel(
    const float* __restrict__ A, const int* __restrict__ bmu,
    const int* __restrict__ epoch_p, const int* __restrict__ maxep_p,
    float* __restrict__ num, float* __restrict__ denom)
{
    int b = blockIdx.x, d = threadIdx.x;  // 512 threads = D
    int ep = epoch_p[0], me = maxep_p[0];
    float progress = (me > 0) ? (float)(me - ep) / (float)me : 0.f;
    progress = fminf(fmaxf(progress, 0.f), 1.f);
    float p2 = progress * progress;
    int ctx = (int)(p2 * p2 * 2.0f);          // CTX_MIN=0, CTX_MAX=2
    float lr = 0.05f + progress * 0.15f;

    int bm = bmu[b];
    int i0 = bm % G_;   // compared against first grid axis (bmu_y convention)
    int j0 = bm / G_;   // compared against second grid axis (bmu_x convention)
    float x = A[(size_t)b * D_ + d];

    for (int di = -ctx; di <= ctx; di++) {
        int i = i0 + di; if (i < 0 || i >= G_) continue;
        for (int dj = -ctx; dj <= ctx; dj++) {
            int j = j0 + dj; if (j < 0 || j >= G_) continue;
            int ad = abs(di), aj = abs(dj);
            int cheb = ad > aj ? ad : aj;
            float coef = ldexpf(lr, -cheb);   // lr / 2^cheb, exact
            atomicAdd(&num[(size_t)(i * G_ + j) * D_ + d], coef * x);
            if (d == 0) atomicAdd(&denom[i * G_ + j], coef);
        }
    }
}

// ---------------- final new_som ----------------
__global__ __launch_bounds__(256) void final_kernel(
    const float* __restrict__ som, const float* __restrict__ num,
    const float* __restrict__ denom, const float* __restrict__ sum_min,
    float* __restrict__ out1)
{
    size_t i4 = (size_t)blockIdx.x * blockDim.x + threadIdx.x;  // float4 index
    if (i4 >= (size_t)N_ * D_ / 4) return;
    int n = (int)(i4 >> 7);           // 128 float4 per cell row
    bool gate = sum_min[0] > 1e-4f * (float)B_;   // mean(min_dists) > 1e-4
    float4 s = ((const float4*)som)[i4];
    float4 o = s;
    if (gate) {
        float4 nu = ((const float4*)num)[i4];
        float dn = denom[n];
        o.x = s.x + nu.x - s.x * dn;
        o.y = s.y + nu.y - s.y * dn;
        o.z = s.z + nu.z - s.z * dn;
        o.w = s.w + nu.w - s.w * dn;
    }
    ((float4*)out1)[i4] = o;
}

extern "C" void kernel_launch(void* const* d_in, const int* in_sizes, int n_in,
                              void* d_out, int out_size, void* d_ws, size_t ws_size,
                              hipStream_t stream) {
    const float* A   = (const float*)d_in[0];   // activations [B][D]
    const int*   lab = (const int*)d_in[1];     // labels [B]
    const float* W   = (const float*)d_in[2];   // som_vectors [G*G][D]
    const int*   cl  = (const int*)d_in[3];     // cell_labels [G*G]
    const float* cr  = (const float*)d_in[4];   // cell_reliability [G*G]
    const int*   ep  = (const int*)d_in[5];     // epoch
    const int*   me  = (const int*)d_in[6];     // max_epochs

    float* out0 = (float*)d_out;                // som_errors [B][D]
    float* out1 = out0 + (size_t)B_ * D_;       // new_som [G*G][D]

    const size_t MB = 1024 * 1024;
    uint8_t* w = (uint8_t*)d_ws;
    float* num     = (float*)(w);                       // 32 MB
    float* pminv   = (float*)(w + 32 * MB);             // 2 MB
    int*   pmini   = (int*)  (w + 34 * MB);             // 2 MB
    float* pcminv  = (float*)(w + 36 * MB);             // 2 MB
    int*   pcmini  = (int*)  (w + 38 * MB);             // 2 MB
    float* wnorm   = (float*)(w + 40 * MB);             // 64 KB
    float* denom   = (float*)(w + 40 * MB + 64 * 1024); // 64 KB
    int*   bmu     = (int*)  (w + 40 * MB + 128 * 1024);// 16 KB
    float* sum_min = (float*)(w + 40 * MB + 144 * 1024);// 4 B

    hipMemsetAsync(num, 0, (size_t)N_ * D_ * sizeof(float), stream);
    hipMemsetAsync(denom, 0, (size_t)N_ * sizeof(float), stream);
    hipMemsetAsync(sum_min, 0, sizeof(float), stream);

    wnorm_kernel<<<N_, 64, 0, stream>>>(W, wnorm);

    dim3 sg(NT, B_ / BM);   // (128, 32)
    score_kernel<<<sg, 256, 0, stream>>>(A, W, wnorm, lab, cl,
                                         pminv, pmini, pcminv, pcmini);

    reduce_kernel<<<B_, 128, 0, stream>>>(A, W, cr, pminv, pmini, pcminv, pcmini,
                                          bmu, sum_min, out0);

    scatter_kernel<<<B_, 512, 0, stream>>>(A, bmu, ep, me, num, denom);

    final_kernel<<<(N_ * D_ / 4 + 255) / 256, 256, 0, stream>>>(
        W, num, denom, sum_min, out1);
}

// Round 2
// 668.767 us; speedup vs baseline: 1.5066x; 1.5066x over previous
//
#include <hip/hip_runtime.h>
#include <hip/hip_bf16.h>
#include <math.h>

#define B_ 4096
#define D_ 512
#define G_ 128
#define N_ (G_*G_)        // 16384
#define NT 128            // number of 128-wide n tiles
#define THR_ 0.95f
#define IMAX_ 0x7FFFFFFF

typedef float f32x4 __attribute__((ext_vector_type(4)));
typedef _Float16 half8 __attribute__((ext_vector_type(8)));

// ---------------- split fp32 -> f16 hi + f16 lo ----------------
__global__ __launch_bounds__(256) void split_kernel(const float* __restrict__ src,
                                                    _Float16* __restrict__ hi,
                                                    _Float16* __restrict__ lo, int n4) {
    int i = blockIdx.x * 256 + threadIdx.x;
    if (i >= n4) return;
    float4 v = ((const float4*)src)[i];
    float vv[4] = {v.x, v.y, v.z, v.w};
    union { _Float16 h[4]; ushort2 u2[2]; uint64_t u64; } H, L;
    #pragma unroll
    for (int j = 0; j < 4; j++) {
        _Float16 h = (_Float16)vv[j];
        H.h[j] = h;
        L.h[j] = (_Float16)(vv[j] - (float)h);
    }
    ((uint64_t*)hi)[i] = H.u64;
    ((uint64_t*)lo)[i] = L.u64;
}

// ---------------- wnorm: ||w_n||^2 (fp32 exact) ----------------
__global__ __launch_bounds__(64) void wnorm_kernel(const float* __restrict__ W,
                                                   float* __restrict__ wnorm) {
    int n = blockIdx.x;
    int t = threadIdx.x;
    const float4* row = (const float4*)(W + (size_t)n * D_);
    float4 a = row[t];
    float4 b = row[t + 64];
    float s = a.x*a.x + a.y*a.y + a.z*a.z + a.w*a.w
            + b.x*b.x + b.y*b.y + b.z*b.z + b.w*b.w;
    #pragma unroll
    for (int off = 32; off > 0; off >>= 1) s += __shfl_down(s, off, 64);
    if (t == 0) wnorm[n] = s;
}

// ---------------- MFMA score GEMM + fused per-tile argmin ----------------
// dot(x,w) = xhi.whi + xhi.wlo + xlo.whi  (virtual K = 3*512)
// score    = wnorm[n] - 2*dot  (x_norm added per-row later; doesn't affect argmin)
__global__ __launch_bounds__(256) void score_mfma_kernel(
    const _Float16* __restrict__ Ahi, const _Float16* __restrict__ Alo,
    const _Float16* __restrict__ Whi, const _Float16* __restrict__ Wlo,
    const float* __restrict__ wnorm,
    const int* __restrict__ labels, const int* __restrict__ clabels,
    float* __restrict__ pminv, int* __restrict__ pmini,
    float* __restrict__ pcminv, int* __restrict__ pcmini)
{
    __shared__ __align__(16) char smem[16384];
    _Float16* As = (_Float16*)smem;            // [128][32]
    _Float16* Bs = (_Float16*)(smem + 8192);   // [128][32]

    const int tid  = threadIdx.x;
    const int lane = tid & 63;
    const int wave = tid >> 6;
    const int wm = wave >> 1, wn = wave & 1;   // 2x2 wave grid, 64x64 per wave
    const int m0 = blockIdx.y * 128;
    const int n0 = blockIdx.x * 128;
    const int c = lane & 15, quad = lane >> 4;
    const int lr = lane >> 2;                  // staging row within 16
    const int lq = (lane & 3) * 8;             // staging k offset (8 f16 = 16B)

    f32x4 acc[4][4];
    #pragma unroll
    for (int i = 0; i < 4; i++)
        #pragma unroll
        for (int j = 0; j < 4; j++)
            acc[i][j] = (f32x4){0.f, 0.f, 0.f, 0.f};

    const _Float16* Aph[3] = {Ahi, Ahi, Alo};
    const _Float16* Wph[3] = {Whi, Wlo, Whi};

    for (int ph = 0; ph < 3; ph++) {
        const _Float16* Ap = Aph[ph];
        const _Float16* Wp = Wph[ph];
        for (int k0 = 0; k0 < D_; k0 += 32) {
            __syncthreads();   // previous iteration's LDS reads complete
            #pragma unroll
            for (int r2 = 0; r2 < 2; r2++) {
                int row = r2 * 64 + wave * 16 + lr;   // 0..127, each exactly once
                const _Float16* gA = Ap + (size_t)(m0 + row) * D_ + k0 + lq;
                const _Float16* gB = Wp + (size_t)(n0 + row) * D_ + k0 + lq;
                // LDS dest: wave-uniform base + lane*16 == &As[row*32 + lq]
                __builtin_amdgcn_global_load_lds(
                    (const __attribute__((address_space(1))) void*)gA,
                    (__attribute__((address_space(3))) void*)&As[row * 32 + lq], 16, 0, 0);
                __builtin_amdgcn_global_load_lds(
                    (const __attribute__((address_space(1))) void*)gB,
                    (__attribute__((address_space(3))) void*)&Bs[row * 32 + lq], 16, 0, 0);
            }
            __syncthreads();   // staging visible
            half8 af[4], bf[4];
            #pragma unroll
            for (int i = 0; i < 4; i++) {
                af[i] = *(const half8*)&As[(wm * 64 + i * 16 + c) * 32 + quad * 8];
                bf[i] = *(const half8*)&Bs[(wn * 64 + i * 16 + c) * 32 + quad * 8];
            }
            #pragma unroll
            for (int i = 0; i < 4; i++)
                #pragma unroll
                for (int j = 0; j < 4; j++)
                    acc[i][j] = __builtin_amdgcn_mfma_f32_16x16x32_f16(af[i], bf[j], acc[i][j], 0, 0, 0);
        }
    }
    __syncthreads();   // done with As/Bs; reuse smem for reduction staging

    // per-lane epilogue: score s = wnorm[n] - 2*acc; argmin over (ni, c)
    float wnl[4]; int cll[4];
    #pragma unroll
    for (int ni = 0; ni < 4; ni++) {
        int n = n0 + wn * 64 + ni * 16 + c;
        wnl[ni] = wnorm[n];
        cll[ni] = clabels[n];
    }

    float* redv = (float*)smem;                 // [2][128]
    int*   redi = (int*)(smem + 1024);          // [2][128]
    float* rcv  = (float*)(smem + 2048);        // [2][128]
    int*   rci  = (int*)(smem + 3072);          // [2][128]

    #pragma unroll
    for (int mi = 0; mi < 4; mi++) {
        #pragma unroll
        for (int r = 0; r < 4; r++) {
            int rowg = wm * 64 + mi * 16 + quad * 4 + r;   // 0..127 in block
            int lb = labels[m0 + rowg];
            float bv = INFINITY; int bn = IMAX_;
            float cv = INFINITY; int cn = IMAX_;
            #pragma unroll
            for (int ni = 0; ni < 4; ni++) {
                float s = fmaf(-2.f, acc[mi][ni][r], wnl[ni]);
                int n = n0 + wn * 64 + ni * 16 + c;
                if (s < bv || (s == bv && n < bn)) { bv = s; bn = n; }
                float cs = (cll[ni] == lb) ? s : INFINITY;
                if (cs < cv || (cs == cv && n < cn)) { cv = cs; cn = n; }
            }
            #pragma unroll
            for (int off = 1; off < 16; off <<= 1) {   // butterfly over c (stays in quad)
                float ov = __shfl_xor(bv, off, 64); int on = __shfl_xor(bn, off, 64);
                if (ov < bv || (ov == bv && on < bn)) { bv = ov; bn = on; }
                float ocv = __shfl_xor(cv, off, 64); int ocn = __shfl_xor(cn, off, 64);
                if (ocv < cv || (ocv == cv && ocn < cn)) { cv = ocv; cn = ocn; }
            }
            if (c == 0) {
                redv[wn * 128 + rowg] = bv; redi[wn * 128 + rowg] = bn;
                rcv [wn * 128 + rowg] = cv; rci [wn * 128 + rowg] = cn;
            }
        }
    }
    __syncthreads();
    if (tid < 128) {
        float bv = redv[tid];      int bn = redi[tid];
        float ov = redv[128 + tid]; int on = redi[128 + tid];
        if (ov < bv || (ov == bv && on < bn)) { bv = ov; bn = on; }
        float cv = rcv[tid];       int cn = rci[tid];
        float ocv = rcv[128 + tid]; int ocn = rci[128 + tid];
        if (ocv < cv || (ocv == cv && ocn < cn)) { cv = ocv; cn = ocn; }
        size_t p = (size_t)(m0 + tid) * NT + blockIdx.x;
        pminv[p] = bv; pmini[p] = bn; pcminv[p] = cv; pcmini[p] = cn;
    }
}

// ---------------- reduce partials per row; emit bmu, sum(min_dists), som_errors ----------------
__global__ __launch_bounds__(128) void reduce_kernel(
    const float* __restrict__ A, const float* __restrict__ W,
    const float* __restrict__ crel,
    const float* __restrict__ pminv, const int* __restrict__ pmini,
    const float* __restrict__ pcminv, const int* __restrict__ pcmini,
    int* __restrict__ bmu, float* __restrict__ sum_min, float* __restrict__ out0)
{
    int b = blockIdx.x, t = threadIdx.x;
    __shared__ float sv[128]; __shared__ int si[128];
    __shared__ float scv[128]; __shared__ int sci[128];
    __shared__ float xs[128];
    __shared__ int   cbmu_s;

    size_t p = (size_t)b * NT + t;
    sv[t] = pminv[p]; si[t] = pmini[p]; scv[t] = pcminv[p]; sci[t] = pcmini[p];

    float4 x4 = ((const float4*)(A + (size_t)b * D_))[t];
    xs[t] = x4.x*x4.x + x4.y*x4.y + x4.z*x4.z + x4.w*x4.w;
    __syncthreads();
    for (int s = 64; s > 0; s >>= 1) {
        if (t < s) {
            float v = sv[t+s]; int idx = si[t+s];
            if (v < sv[t] || (v == sv[t] && idx < si[t])) { sv[t] = v; si[t] = idx; }
            v = scv[t+s]; idx = sci[t+s];
            if (v < scv[t] || (v == scv[t] && idx < sci[t])) { scv[t] = v; sci[t] = idx; }
            xs[t] += xs[t+s];
        }
        __syncthreads();
    }
    if (t == 0) {
        bmu[b] = si[0];
        float md = xs[0] + sv[0];
        if (md < 0.f) md = 0.f;
        atomicAdd(sum_min, md);
        cbmu_s = sci[0];
    }
    __syncthreads();
    int cb = cbmu_s;
    float r = crel[cb] / 100.0f;
    float val = (r >= THR_) ? 1.0f : 0.0f;
    float sc = 0.01f * r * val;
    float4 w4 = ((const float4*)(W + (size_t)cb * D_))[t];
    float4 o;
    o.x = sc * (w4.x - x4.x); o.y = sc * (w4.y - x4.y);
    o.z = sc * (w4.z - x4.z); o.w = sc * (w4.w - x4.w);
    ((float4*)(out0 + (size_t)b * D_))[t] = o;
}

// ---------------- neighborhood scatter (atomic into out1-as-num) ----------------
__global__ __launch_bounds__(512) void scatter_kernel(
    const float* __restrict__ A, const int* __restrict__ bmu,
    const int* __restrict__ epoch_p, const int* __restrict__ maxep_p,
    float* num, float* __restrict__ denom)
{
    int b = blockIdx.x, d = threadIdx.x;
    int ep = epoch_p[0], me = maxep_p[0];
    float progress = (me > 0) ? (float)(me - ep) / (float)me : 0.f;
    progress = fminf(fmaxf(progress, 0.f), 1.f);
    float p2 = progress * progress;
    int ctx = (int)(p2 * p2 * 2.0f);          // CTX_MIN=0, CTX_MAX=2
    float lr = 0.05f + progress * 0.15f;

    int bm = bmu[b];
    int i0 = bm % G_;
    int j0 = bm / G_;
    float x = A[(size_t)b * D_ + d];

    for (int di = -ctx; di <= ctx; di++) {
        int i = i0 + di; if (i < 0 || i >= G_) continue;
        for (int dj = -ctx; dj <= ctx; dj++) {
            int j = j0 + dj; if (j < 0 || j >= G_) continue;
            int ad = abs(di), aj = abs(dj);
            int cheb = ad > aj ? ad : aj;
            float coef = ldexpf(lr, -cheb);   // lr / 2^cheb, exact
            atomicAdd(&num[(size_t)(i * G_ + j) * D_ + d], coef * x);
            if (d == 0) atomicAdd(&denom[i * G_ + j], coef);
        }
    }
}

// ---------------- final new_som (in-place: out1 holds num on entry) ----------------
__global__ __launch_bounds__(256) void final_kernel(
    const float* __restrict__ som, const float* __restrict__ denom,
    const float* __restrict__ sum_min, float* out1)
{
    size_t i4 = (size_t)blockIdx.x * blockDim.x + threadIdx.x;
    if (i4 >= (size_t)N_ * D_ / 4) return;
    int n = (int)(i4 >> 7);
    bool gate = sum_min[0] > 1e-4f * (float)B_;
    float4 s = ((const float4*)som)[i4];
    float4 o = s;
    if (gate) {
        float4 nu = ((float4*)out1)[i4];
        float dn = denom[n];
        o.x = s.x + nu.x - s.x * dn;
        o.y = s.y + nu.y - s.y * dn;
        o.z = s.z + nu.z - s.z * dn;
        o.w = s.w + nu.w - s.w * dn;
    }
    ((float4*)out1)[i4] = o;
}

extern "C" void kernel_launch(void* const* d_in, const int* in_sizes, int n_in,
                              void* d_out, int out_size, void* d_ws, size_t ws_size,
                              hipStream_t stream) {
    const float* A   = (const float*)d_in[0];   // activations [B][D]
    const int*   lab = (const int*)d_in[1];     // labels [B]
    const float* W   = (const float*)d_in[2];   // som_vectors [G*G][D]
    const int*   cl  = (const int*)d_in[3];     // cell_labels [G*G]
    const float* cr  = (const float*)d_in[4];   // cell_reliability [G*G]
    const int*   ep  = (const int*)d_in[5];     // epoch
    const int*   me  = (const int*)d_in[6];     // max_epochs

    float* out0 = (float*)d_out;                // som_errors [B][D]
    float* out1 = out0 + (size_t)B_ * D_;       // new_som [G*G][D] (used as num first)

    const size_t MB = 1024 * 1024;
    uint8_t* w = (uint8_t*)d_ws;
    _Float16* Ahi  = (_Float16*)(w);                    //  4 MB
    _Float16* Alo  = (_Float16*)(w + 4 * MB);           //  4 MB
    _Float16* Whi  = (_Float16*)(w + 8 * MB);           // 16 MB
    _Float16* Wlo  = (_Float16*)(w + 24 * MB);          // 16 MB
    float* pminv   = (float*)(w + 40 * MB);             //  2 MB
    int*   pmini   = (int*)  (w + 42 * MB);             //  2 MB
    float* pcminv  = (float*)(w + 44 * MB);             //  2 MB
    int*   pcmini  = (int*)  (w + 46 * MB);             //  2 MB
    float* wnorm   = (float*)(w + 48 * MB);             // 64 KB
    float* denom   = (float*)(w + 48 * MB + 64 * 1024); // 64 KB
    int*   bmu     = (int*)  (w + 48 * MB + 128 * 1024);// 16 KB
    float* sum_min = (float*)(w + 48 * MB + 144 * 1024);// 4 B

    hipMemsetAsync(out1, 0, (size_t)N_ * D_ * sizeof(float), stream);  // num
    hipMemsetAsync(denom, 0, (size_t)N_ * sizeof(float), stream);
    hipMemsetAsync(sum_min, 0, sizeof(float), stream);

    split_kernel<<<(B_ * D_ / 4 + 255) / 256, 256, 0, stream>>>(A, Ahi, Alo, B_ * D_ / 4);
    split_kernel<<<(N_ * D_ / 4 + 255) / 256, 256, 0, stream>>>(W, Whi, Wlo, N_ * D_ / 4);

    wnorm_kernel<<<N_, 64, 0, stream>>>(W, wnorm);

    dim3 sg(NT, B_ / 128);   // (128, 32)
    score_mfma_kernel<<<sg, 256, 0, stream>>>(Ahi, Alo, Whi, Wlo, wnorm, lab, cl,
                                              pminv, pmini, pcminv, pcmini);

    reduce_kernel<<<B_, 128, 0, stream>>>(A, W, cr, pminv, pmini, pcminv, pcmini,
                                          bmu, sum_min, out0);

    scatter_kernel<<<B_, 512, 0, stream>>>(A, bmu, ep, me, out1, denom);

    final_kernel<<<(N_ * D_ / 4 + 255) / 256, 256, 0, stream>>>(W, denom, sum_min, out1);
}

// Round 3
// 542.080 us; speedup vs baseline: 1.8587x; 1.2337x over previous
//
#include <hip/hip_runtime.h>
#include <hip/hip_bf16.h>
#include <math.h>

#define B_ 4096
#define D_ 512
#define G_ 128
#define N_ (G_*G_)        // 16384
#define NT 128            // number of 128-wide n tiles
#define THR_ 0.95f
#define IMAX_ 0x7FFFFFFF

typedef float f32x4 __attribute__((ext_vector_type(4)));
typedef _Float16 half8 __attribute__((ext_vector_type(8)));

// ---------------- split fp32 -> f16 hi + f16 lo ----------------
__global__ __launch_bounds__(256) void split_kernel(const float* __restrict__ src,
                                                    _Float16* __restrict__ hi,
                                                    _Float16* __restrict__ lo, int n4) {
    int i = blockIdx.x * 256 + threadIdx.x;
    if (i >= n4) return;
    float4 v = ((const float4*)src)[i];
    float vv[4] = {v.x, v.y, v.z, v.w};
    union { _Float16 h[4]; uint64_t u64; } H, L;
    #pragma unroll
    for (int j = 0; j < 4; j++) {
        _Float16 h = (_Float16)vv[j];
        H.h[j] = h;
        L.h[j] = (_Float16)(vv[j] - (float)h);
    }
    ((uint64_t*)hi)[i] = H.u64;
    ((uint64_t*)lo)[i] = L.u64;
}

// ---------------- wnorm: ||w_n||^2 (fp32 exact) ----------------
__global__ __launch_bounds__(64) void wnorm_kernel(const float* __restrict__ W,
                                                   float* __restrict__ wnorm) {
    int n = blockIdx.x;
    int t = threadIdx.x;
    const float4* row = (const float4*)(W + (size_t)n * D_);
    float4 a = row[t];
    float4 b = row[t + 64];
    float s = a.x*a.x + a.y*a.y + a.z*a.z + a.w*a.w
            + b.x*b.x + b.y*b.y + b.z*b.z + b.w*b.w;
    #pragma unroll
    for (int off = 32; off > 0; off >>= 1) s += __shfl_down(s, off, 64);
    if (t == 0) wnorm[n] = s;
}

// ---------------- MFMA score GEMM + fused per-tile argmin ----------------
// dot(x,w) = xhi.whi + xhi.wlo + xlo.whi  (virtual K = 3*512 = 48 BK-32 steps)
// Double-buffered LDS: stage step t+1 into buf (t+1)&1 right after the barrier
// publishing step t, so the vmcnt(0) drain at the NEXT barrier has a full
// iteration of MFMA+ds_read slack (single barrier per iteration).
__global__ __launch_bounds__(256) void score_mfma_kernel(
    const _Float16* __restrict__ Ahi, const _Float16* __restrict__ Alo,
    const _Float16* __restrict__ Whi, const _Float16* __restrict__ Wlo,
    const float* __restrict__ wnorm,
    const int* __restrict__ labels, const int* __restrict__ clabels,
    float* __restrict__ pminv, int* __restrict__ pmini,
    float* __restrict__ pcminv, int* __restrict__ pcmini)
{
    __shared__ __align__(16) char smem[32768];   // 2 x (As 8KB + Bs 8KB)

    const int tid  = threadIdx.x;
    const int lane = tid & 63;
    const int wave = tid >> 6;
    const int wm = wave >> 1, wn = wave & 1;   // 2x2 wave grid, 64x64 per wave
    const int m0 = blockIdx.y * 128;
    const int n0 = blockIdx.x * 128;
    const int c = lane & 15, quad = lane >> 4;
    const int lr = lane >> 2;                  // staging row within 16
    const int lq = (lane & 3) * 8;             // staging k offset (8 f16 = 16B)

    // per-thread staging offsets (element units), constant across iterations
    size_t offA[2], offB[2];
    int    offL[2];
    #pragma unroll
    for (int r2 = 0; r2 < 2; r2++) {
        int row = r2 * 64 + wave * 16 + lr;    // 0..127, each exactly once
        offA[r2] = (size_t)(m0 + row) * D_ + lq;
        offB[r2] = (size_t)(n0 + row) * D_ + lq;
        offL[r2] = row * 32 + lq;
    }

    f32x4 acc[4][4];
    #pragma unroll
    for (int i = 0; i < 4; i++)
        #pragma unroll
        for (int j = 0; j < 4; j++)
            acc[i][j] = (f32x4){0.f, 0.f, 0.f, 0.f};

    // prologue: stage t=0 (phase 0: Ahi x Whi, k0=0) into buf 0
    {
        _Float16* As = (_Float16*)smem;
        _Float16* Bs = (_Float16*)(smem + 8192);
        #pragma unroll
        for (int r2 = 0; r2 < 2; r2++) {
            __builtin_amdgcn_global_load_lds(
                (const __attribute__((address_space(1))) void*)(Ahi + offA[r2]),
                (__attribute__((address_space(3))) void*)(As + offL[r2]), 16, 0, 0);
            __builtin_amdgcn_global_load_lds(
                (const __attribute__((address_space(1))) void*)(Whi + offB[r2]),
                (__attribute__((address_space(3))) void*)(Bs + offL[r2]), 16, 0, 0);
        }
    }

    for (int t = 0; t < 48; t++) {
        __syncthreads();   // publishes buf t&1 (implicit vmcnt drain) + frees buf (t+1)&1
        if (t < 47) {
            int t1 = t + 1;
            const _Float16* Ap = (t1 < 32) ? Ahi : Alo;
            const _Float16* Wp = (t1 < 16) ? Whi : ((t1 < 32) ? Wlo : Whi);
            int k1 = (t1 & 15) << 5;
            char* sb = smem + ((t1 & 1) << 14);
            _Float16* As = (_Float16*)sb;
            _Float16* Bs = (_Float16*)(sb + 8192);
            #pragma unroll
            for (int r2 = 0; r2 < 2; r2++) {
                __builtin_amdgcn_global_load_lds(
                    (const __attribute__((address_space(1))) void*)(Ap + offA[r2] + k1),
                    (__attribute__((address_space(3))) void*)(As + offL[r2]), 16, 0, 0);
                __builtin_amdgcn_global_load_lds(
                    (const __attribute__((address_space(1))) void*)(Wp + offB[r2] + k1),
                    (__attribute__((address_space(3))) void*)(Bs + offL[r2]), 16, 0, 0);
            }
        }
        char* sb = smem + ((t & 1) << 14);
        const _Float16* As = (const _Float16*)sb;
        const _Float16* Bs = (const _Float16*)(sb + 8192);
        half8 af[4], bf[4];
        #pragma unroll
        for (int i = 0; i < 4; i++) {
            af[i] = *(const half8*)&As[(wm * 64 + i * 16 + c) * 32 + quad * 8];
            bf[i] = *(const half8*)&Bs[(wn * 64 + i * 16 + c) * 32 + quad * 8];
        }
        #pragma unroll
        for (int i = 0; i < 4; i++)
            #pragma unroll
            for (int j = 0; j < 4; j++)
                acc[i][j] = __builtin_amdgcn_mfma_f32_16x16x32_f16(af[i], bf[j], acc[i][j], 0, 0, 0);
    }
    __syncthreads();   // done with tiles; reuse smem for reduction staging

    // per-lane epilogue: score s = wnorm[n] - 2*acc; argmin over (ni, c)
    float wnl[4]; int cll[4];
    #pragma unroll
    for (int ni = 0; ni < 4; ni++) {
        int n = n0 + wn * 64 + ni * 16 + c;
        wnl[ni] = wnorm[n];
        cll[ni] = clabels[n];
    }

    float* redv = (float*)smem;                 // [2][128]
    int*   redi = (int*)(smem + 1024);          // [2][128]
    float* rcv  = (float*)(smem + 2048);        // [2][128]
    int*   rci  = (int*)(smem + 3072);          // [2][128]

    #pragma unroll
    for (int mi = 0; mi < 4; mi++) {
        #pragma unroll
        for (int r = 0; r < 4; r++) {
            int rowg = wm * 64 + mi * 16 + quad * 4 + r;   // 0..127 in block
            int lb = labels[m0 + rowg];
            float bv = INFINITY; int bn = IMAX_;
            float cv = INFINITY; int cn = IMAX_;
            #pragma unroll
            for (int ni = 0; ni < 4; ni++) {
                float s = fmaf(-2.f, acc[mi][ni][r], wnl[ni]);
                int n = n0 + wn * 64 + ni * 16 + c;
                if (s < bv || (s == bv && n < bn)) { bv = s; bn = n; }
                float cs = (cll[ni] == lb) ? s : INFINITY;
                if (cs < cv || (cs == cv && n < cn)) { cv = cs; cn = n; }
            }
            #pragma unroll
            for (int off = 1; off < 16; off <<= 1) {   // butterfly over c
                float ov = __shfl_xor(bv, off, 64); int on = __shfl_xor(bn, off, 64);
                if (ov < bv || (ov == bv && on < bn)) { bv = ov; bn = on; }
                float ocv = __shfl_xor(cv, off, 64); int ocn = __shfl_xor(cn, off, 64);
                if (ocv < cv || (ocv == cv && ocn < cn)) { cv = ocv; cn = ocn; }
            }
            if (c == 0) {
                redv[wn * 128 + rowg] = bv; redi[wn * 128 + rowg] = bn;
                rcv [wn * 128 + rowg] = cv; rci [wn * 128 + rowg] = cn;
            }
        }
    }
    __syncthreads();
    if (tid < 128) {
        float bv = redv[tid];      int bn = redi[tid];
        float ov = redv[128 + tid]; int on = redi[128 + tid];
        if (ov < bv || (ov == bv && on < bn)) { bv = ov; bn = on; }
        float cv = rcv[tid];       int cn = rci[tid];
        float ocv = rcv[128 + tid]; int ocn = rci[128 + tid];
        if (ocv < cv || (ocv == cv && ocn < cn)) { cv = ocv; cn = ocn; }
        size_t p = (size_t)(m0 + tid) * NT + blockIdx.x;
        pminv[p] = bv; pmini[p] = bn; pcminv[p] = cv; pcmini[p] = cn;
    }
}

// ---------------- reduce partials per row; emit bmu, sum(min_dists), som_errors ----------------
__global__ __launch_bounds__(128) void reduce_kernel(
    const float* __restrict__ A, const float* __restrict__ W,
    const float* __restrict__ crel,
    const float* __restrict__ pminv, const int* __restrict__ pmini,
    const float* __restrict__ pcminv, const int* __restrict__ pcmini,
    int* __restrict__ bmu, float* __restrict__ sum_min, float* __restrict__ out0)
{
    int b = blockIdx.x, t = threadIdx.x;
    __shared__ float sv[128]; __shared__ int si[128];
    __shared__ float scv[128]; __shared__ int sci[128];
    __shared__ float xs[128];
    __shared__ int   cbmu_s;

    size_t p = (size_t)b * NT + t;
    sv[t] = pminv[p]; si[t] = pmini[p]; scv[t] = pcminv[p]; sci[t] = pcmini[p];

    float4 x4 = ((const float4*)(A + (size_t)b * D_))[t];
    xs[t] = x4.x*x4.x + x4.y*x4.y + x4.z*x4.z + x4.w*x4.w;
    __syncthreads();
    for (int s = 64; s > 0; s >>= 1) {
        if (t < s) {
            float v = sv[t+s]; int idx = si[t+s];
            if (v < sv[t] || (v == sv[t] && idx < si[t])) { sv[t] = v; si[t] = idx; }
            v = scv[t+s]; idx = sci[t+s];
            if (v < scv[t] || (v == scv[t] && idx < sci[t])) { scv[t] = v; sci[t] = idx; }
            xs[t] += xs[t+s];
        }
        __syncthreads();
    }
    if (t == 0) {
        bmu[b] = si[0];
        float md = xs[0] + sv[0];
        if (md < 0.f) md = 0.f;
        atomicAdd(sum_min, md);
        cbmu_s = sci[0];
    }
    __syncthreads();
    int cb = cbmu_s;
    float r = crel[cb] / 100.0f;
    float val = (r >= THR_) ? 1.0f : 0.0f;
    float sc = 0.01f * r * val;
    float4 w4 = ((const float4*)(W + (size_t)cb * D_))[t];
    float4 o;
    o.x = sc * (w4.x - x4.x); o.y = sc * (w4.y - x4.y);
    o.z = sc * (w4.z - x4.z); o.w = sc * (w4.w - x4.w);
    ((float4*)(out0 + (size_t)b * D_))[t] = o;
}

// ---------------- per-BMU accumulate: S[bmu] += A[b], count[bmu] += 1 ----------------
__global__ __launch_bounds__(512) void scatter1_kernel(
    const float* __restrict__ A, const int* __restrict__ bmu,
    float* S, float* count)
{
    int b = blockIdx.x, d = threadIdx.x;
    int bm = bmu[b];
    float x = A[(size_t)b * D_ + d];
    atomicAdd(&S[(size_t)bm * D_ + d], x);
    if (d == 0) atomicAdd(&count[bm], 1.0f);
}

// ---------------- denom via 3x3 (ctx<=2: 5x5) stencil over counts ----------------
__global__ __launch_bounds__(256) void denom_kernel(
    const float* __restrict__ count,
    const int* __restrict__ epoch_p, const int* __restrict__ maxep_p,
    float* __restrict__ denom)
{
    int n = blockIdx.x * 256 + threadIdx.x;
    if (n >= N_) return;
    int ep = epoch_p[0], me = maxep_p[0];
    float progress = (me > 0) ? (float)(me - ep) / (float)me : 0.f;
    progress = fminf(fmaxf(progress, 0.f), 1.f);
    float p2 = progress * progress;
    int ctx = (int)(p2 * p2 * 2.0f);
    float lr = 0.05f + progress * 0.15f;

    int i = n / G_, j = n % G_;   // num flat index convention: n = i*G + j
    float s = 0.f;
    for (int di = -ctx; di <= ctx; di++) {
        int ia = i - di; if (ia < 0 || ia >= G_) continue;
        for (int dj = -ctx; dj <= ctx; dj++) {
            int jb = j - dj; if (jb < 0 || jb >= G_) continue;
            int ad = abs(di), aj = abs(dj);
            int cheb = ad > aj ? ad : aj;
            s += ldexpf(lr, -cheb) * count[jb * G_ + ia];
        }
    }
    denom[n] = s;
}

// ---------------- final: out1 = som + stencil(S) - som*denom (gated) ----------------
__global__ __launch_bounds__(256) void final_kernel(
    const float* __restrict__ som, const float* __restrict__ S,
    const float* __restrict__ denom, const float* __restrict__ sum_min,
    const int* __restrict__ epoch_p, const int* __restrict__ maxep_p,
    float* __restrict__ out1)
{
    size_t i4 = (size_t)blockIdx.x * 256 + threadIdx.x;
    if (i4 >= (size_t)N_ * D_ / 4) return;
    int n = (int)(i4 >> 7);          // 128 float4 per cell row
    int d4 = (int)(i4 & 127);
    float4 s = ((const float4*)som)[i4];
    bool gate = sum_min[0] > 1e-4f * (float)B_;   // mean(min_dists) > 1e-4
    float4 o = s;
    if (gate) {
        int ep = epoch_p[0], me = maxep_p[0];
        float progress = (me > 0) ? (float)(me - ep) / (float)me : 0.f;
        progress = fminf(fmaxf(progress, 0.f), 1.f);
        float p2 = progress * progress;
        int ctx = (int)(p2 * p2 * 2.0f);
        float lr = 0.05f + progress * 0.15f;

        int i = n / G_, j = n % G_;
        float4 nu = {0.f, 0.f, 0.f, 0.f};
        for (int di = -ctx; di <= ctx; di++) {
            int ia = i - di; if (ia < 0 || ia >= G_) continue;
            for (int dj = -ctx; dj <= ctx; dj++) {
                int jb = j - dj; if (jb < 0 || jb >= G_) continue;
                int ad = abs(di), aj = abs(dj);
                int cheb = ad > aj ? ad : aj;
                float coef = ldexpf(lr, -cheb);
                float4 t4 = ((const float4*)S)[(size_t)(jb * G_ + ia) * 128 + d4];
                nu.x += coef * t4.x; nu.y += coef * t4.y;
                nu.z += coef * t4.z; nu.w += coef * t4.w;
            }
        }
        float dn = denom[n];
        o.x = s.x + nu.x - s.x * dn;
        o.y = s.y + nu.y - s.y * dn;
        o.z = s.z + nu.z - s.z * dn;
        o.w = s.w + nu.w - s.w * dn;
    }
    ((float4*)out1)[i4] = o;
}

extern "C" void kernel_launch(void* const* d_in, const int* in_sizes, int n_in,
                              void* d_out, int out_size, void* d_ws, size_t ws_size,
                              hipStream_t stream) {
    const float* A   = (const float*)d_in[0];   // activations [B][D]
    const int*   lab = (const int*)d_in[1];     // labels [B]
    const float* W   = (const float*)d_in[2];   // som_vectors [G*G][D]
    const int*   cl  = (const int*)d_in[3];     // cell_labels [G*G]
    const float* cr  = (const float*)d_in[4];   // cell_reliability [G*G]
    const int*   ep  = (const int*)d_in[5];     // epoch
    const int*   me  = (const int*)d_in[6];     // max_epochs

    float* out0 = (float*)d_out;                // som_errors [B][D]
    float* out1 = out0 + (size_t)B_ * D_;       // new_som [G*G][D]

    const size_t MB = 1024 * 1024;
    uint8_t* w = (uint8_t*)d_ws;
    // phase 1 (score): split buffers occupy [0, 40 MB)
    _Float16* Ahi  = (_Float16*)(w);                    //  4 MB
    _Float16* Alo  = (_Float16*)(w + 4 * MB);           //  4 MB
    _Float16* Whi  = (_Float16*)(w + 8 * MB);           // 16 MB
    _Float16* Wlo  = (_Float16*)(w + 24 * MB);          // 16 MB
    // phase 2 (update): S aliases the dead split region [0, 32 MB)
    float* S       = (float*)(w);                       // 32 MB (after score)
    float* pminv   = (float*)(w + 40 * MB);             //  2 MB
    int*   pmini   = (int*)  (w + 42 * MB);             //  2 MB
    float* pcminv  = (float*)(w + 44 * MB);             //  2 MB
    int*   pcmini  = (int*)  (w + 46 * MB);             //  2 MB
    float* wnorm   = (float*)(w + 48 * MB);             // 64 KB
    float* denom   = (float*)(w + 48 * MB + 64 * 1024); // 64 KB
    float* count   = (float*)(w + 48 * MB + 128 * 1024);// 64 KB
    int*   bmu     = (int*)  (w + 48 * MB + 192 * 1024);// 64 KB
    float* sum_min = (float*)(w + 48 * MB + 256 * 1024);// 4 B

    hipMemsetAsync(sum_min, 0, sizeof(float), stream);

    split_kernel<<<(B_ * D_ / 4 + 255) / 256, 256, 0, stream>>>(A, Ahi, Alo, B_ * D_ / 4);
    split_kernel<<<(N_ * D_ / 4 + 255) / 256, 256, 0, stream>>>(W, Whi, Wlo, N_ * D_ / 4);

    wnorm_kernel<<<N_, 64, 0, stream>>>(W, wnorm);

    dim3 sg(NT, B_ / 128);   // (128, 32)
    score_mfma_kernel<<<sg, 256, 0, stream>>>(Ahi, Alo, Whi, Wlo, wnorm, lab, cl,
                                              pminv, pmini, pcminv, pcmini);

    reduce_kernel<<<B_, 128, 0, stream>>>(A, W, cr, pminv, pmini, pcminv, pcmini,
                                          bmu, sum_min, out0);

    // split buffers are dead now; reuse as S (stream-ordered)
    hipMemsetAsync(S, 0, (size_t)N_ * D_ * sizeof(float), stream);
    hipMemsetAsync(count, 0, (size_t)N_ * sizeof(float), stream);

    scatter1_kernel<<<B_, 512, 0, stream>>>(A, bmu, S, count);

    denom_kernel<<<(N_ + 255) / 256, 256, 0, stream>>>(count, ep, me, denom);

    final_kernel<<<(N_ * D_ / 4 + 255) / 256, 256, 0, stream>>>(
        W, S, denom, sum_min, ep, me, out1);
}